// Round 1
// baseline (59.447 us; speedup 1.0000x reference)
//
#include <hip/hip_runtime.h>

// Sliding-window min (STL Always_[16,64]):
//   out[t][b] = min_{j=15..63} xpad[t-j][b],   xpad[s<0] = 1e6
// Window width 49 along T. Memory-bound: 256 MiB min traffic -> ~40us.

#define T_DIM 8192
#define B_DIM 4096
#define C_TILE 32               // outputs per thread along T
#define ALEN (C_TILE + 48)      // inputs per thread (window width 49)
#define LARGE_VAL 1e6f

__global__ __launch_bounds__(256)
void Temporal_Operator_kernel(const float* __restrict__ x,
                              float* __restrict__ out) {
    const int b  = blockIdx.x * blockDim.x + threadIdx.x;   // column
    const int t0 = blockIdx.y * C_TILE;                     // output tile start
    const long base = (long)t0 - 63;                        // first input row

    // Load inputs (negative rows -> LARGE). All indices compile-time after
    // unroll so arr[] stays in VGPRs. s>=0 is wave-uniform -> scalar branch.
    float arr[ALEN];
    #pragma unroll
    for (int i = 0; i < ALEN; ++i) {
        long s = base + i;
        arr[i] = (s >= 0) ? x[s * B_DIM + b] : LARGE_VAL;
    }

    // Log-doubling forward window mins, in place:
    // after pass k, arr[i] = min(x[i .. i+k-1]) for the valid range.
    #pragma unroll
    for (int i = 0; i < ALEN - 1; ++i)  arr[i] = fminf(arr[i], arr[i + 1]);   // w2
    #pragma unroll
    for (int i = 0; i < ALEN - 3; ++i)  arr[i] = fminf(arr[i], arr[i + 2]);   // w4
    #pragma unroll
    for (int i = 0; i < ALEN - 7; ++i)  arr[i] = fminf(arr[i], arr[i + 4]);   // w8
    #pragma unroll
    for (int i = 0; i < ALEN - 15; ++i) arr[i] = fminf(arr[i], arr[i + 8]);   // w16
    #pragma unroll
    for (int i = 0; i < ALEN - 31; ++i) arr[i] = fminf(arr[i], arr[i + 16]);  // w32

    // w49[c] = min(w32[c], w32[c+17])  covers [c, c+48]
    #pragma unroll
    for (int c = 0; c < C_TILE; ++c) {
        out[(long)(t0 + c) * B_DIM + b] = fminf(arr[c], arr[c + 17]);
    }
}

extern "C" void kernel_launch(void* const* d_in, const int* in_sizes, int n_in,
                              void* d_out, int out_size, void* d_ws, size_t ws_size,
                              hipStream_t stream) {
    const float* x = (const float*)d_in[0];
    float* out = (float*)d_out;

    dim3 block(256, 1, 1);
    dim3 grid(B_DIM / 256, T_DIM / C_TILE, 1);   // 16 x 256 blocks
    Temporal_Operator_kernel<<<grid, block, 0, stream>>>(x, out);
}